// Round 1
// baseline (561.318 us; speedup 1.0000x reference)
//
#include <hip/hip_runtime.h>
#include <hip/hip_bf16.h>

// ---------------------------------------------------------------------------
// AttentionBlock: GroupNorm -> q,k,v 1x1 conv -> softmax(-128 * q^T k) -> PV
//                 + conv1x1(x, Wo)
// B=8, C=256, HW=4096, 32 groups. fp32 in/out.
// Precision: scores need bf16x2 split (3-MFMA) path; V/PV/out-proj plain bf16.
// ---------------------------------------------------------------------------

typedef __attribute__((ext_vector_type(8))) short bf16x8;
typedef __attribute__((ext_vector_type(4))) short s16x4;
typedef __attribute__((ext_vector_type(8))) short s16x8;
typedef __attribute__((ext_vector_type(4))) float f32x4;

#define MFMA16(a, b, c) __builtin_amdgcn_mfma_f32_16x16x32_bf16((a), (b), (c), 0, 0, 0)

// -0.5 * C * log2(e): fold attention scale (and exp->exp2) into q.
#define SCALE_Q (-184.66496523378734f)

__device__ __forceinline__ short f2bf(float f) {
  unsigned int u = __builtin_bit_cast(unsigned int, f);
  u = (u + 0x7FFFu + ((u >> 16) & 1u)) >> 16;
  return (short)(unsigned short)u;
}
__device__ __forceinline__ float bf2f(short h) {
  unsigned int u = ((unsigned int)(unsigned short)h) << 16;
  return __builtin_bit_cast(float, u);
}
__device__ __forceinline__ void async16(void* lds, const void* g) {
  __builtin_amdgcn_global_load_lds(
      (const __attribute__((address_space(1))) unsigned int*)g,
      (__attribute__((address_space(3))) unsigned int*)lds, 16, 0, 0);
}

// --------------------------- W -> hi/lo bf16 split -------------------------
__global__ void wsplit_k(const float* __restrict__ Wq, const float* __restrict__ Wk,
                         const float* __restrict__ Wv, const float* __restrict__ Wo,
                         short* __restrict__ whi, short* __restrict__ wlo) {
  int idx = blockIdx.x * 256 + threadIdx.x;   // 0 .. 4*65536-1
  int m = idx >> 16;
  int e = idx & 65535;
  const float* W = (m == 0) ? Wq : (m == 1) ? Wk : (m == 2) ? Wv : Wo;
  float v = W[e];
  short h = f2bf(v);
  whi[idx] = h;
  wlo[idx] = f2bf(v - bf2f(h));
}

// --------------------------- GroupNorm stats -------------------------------
__global__ void gn_stats_k(const float* __restrict__ x, float* __restrict__ stats) {
  int bg = blockIdx.x;          // b*32 + g, contiguous 32768 floats
  int tid = threadIdx.x;
  const float* p = x + (size_t)bg * 32768;
  float s = 0.f, sq = 0.f;
  for (int it = 0; it < 32; ++it) {
    f32x4 v = *(const f32x4*)(p + (size_t)(it * 256 + tid) * 4);
    s += v[0] + v[1] + v[2] + v[3];
    sq += v[0] * v[0] + v[1] * v[1] + v[2] * v[2] + v[3] * v[3];
  }
#pragma unroll
  for (int off = 1; off < 64; off <<= 1) {
    s += __shfl_xor(s, off);
    sq += __shfl_xor(sq, off);
  }
  __shared__ float ls[4], lq[4];
  int w = tid >> 6;
  if ((tid & 63) == 0) { ls[w] = s; lq[w] = sq; }
  __syncthreads();
  if (tid == 0) {
    float S = ls[0] + ls[1] + ls[2] + ls[3];
    float Q = lq[0] + lq[1] + lq[2] + lq[3];
    float mean = S * (1.f / 32768.f);
    float var = Q * (1.f / 32768.f) - mean * mean;
    stats[bg * 2] = mean;
    stats[bg * 2 + 1] = rsqrtf(var + 1e-5f);
  }
}

// ------------------- GroupNorm apply + transpose + split -------------------
// x[b][c][i] fp32 -> hnT[b][i][c] bf16 hi/lo  (c contiguous)
__global__ void gn_apply_k(const float* __restrict__ x, const float* __restrict__ gamma,
                           const float* __restrict__ beta, const float* __restrict__ stats,
                           short* __restrict__ hn_hi, short* __restrict__ hn_lo) {
  __shared__ float tile[64 * 68];
  int tid = threadIdx.x;
  int b = blockIdx.z, c0 = blockIdx.y * 64, i0 = blockIdx.x * 64;
  int cc = tid >> 4, ich = tid & 15;
#pragma unroll
  for (int it = 0; it < 4; ++it) {
    int c = c0 + cc + it * 16;
    f32x4 vx = *(const f32x4*)(x + ((size_t)(b * 256 + c)) * 4096 + i0 + ich * 4);
    float mean = stats[(b * 32 + (c >> 3)) * 2];
    float rstd = stats[(b * 32 + (c >> 3)) * 2 + 1];
    float ga = gamma[c] * rstd;
    float be = beta[c] - mean * ga;
    f32x4 h = {vx[0] * ga + be, vx[1] * ga + be, vx[2] * ga + be, vx[3] * ga + be};
    *(f32x4*)(&tile[(cc + it * 16) * 68 + ich * 4]) = h;
  }
  __syncthreads();
  int il = tid >> 2, ch = tid & 3;
  s16x8 hv0, hv1, lv0, lv1;
#pragma unroll
  for (int u = 0; u < 16; ++u) {
    float vv = tile[(ch * 16 + u) * 68 + il];
    short h = f2bf(vv);
    short lo = f2bf(vv - bf2f(h));
    if (u < 8) { hv0[u] = h; lv0[u] = lo; } else { hv1[u - 8] = h; lv1[u - 8] = lo; }
  }
  size_t ro = ((size_t)(b * 4096 + i0 + il)) * 256 + c0 + ch * 16;
  *(s16x8*)(hn_hi + ro) = hv0;
  *(s16x8*)(hn_hi + ro + 8) = hv1;
  *(s16x8*)(hn_lo + ro) = lv0;
  *(s16x8*)(hn_lo + ro + 8) = lv1;
}

// --------------------- x transpose to bf16 (for out-proj) ------------------
__global__ void xt_k(const float* __restrict__ x, short* __restrict__ xt) {
  __shared__ float tile[64 * 68];
  int tid = threadIdx.x;
  int b = blockIdx.z, c0 = blockIdx.y * 64, i0 = blockIdx.x * 64;
  int cc = tid >> 4, ich = tid & 15;
#pragma unroll
  for (int it = 0; it < 4; ++it) {
    int c = c0 + cc + it * 16;
    f32x4 vx = *(const f32x4*)(x + ((size_t)(b * 256 + c)) * 4096 + i0 + ich * 4);
    *(f32x4*)(&tile[(cc + it * 16) * 68 + ich * 4]) = vx;
  }
  __syncthreads();
  int il = tid >> 2, ch = tid & 3;
  s16x8 hv0, hv1;
#pragma unroll
  for (int u = 0; u < 16; ++u) {
    float vv = tile[(ch * 16 + u) * 68 + il];
    short h = f2bf(vv);
    if (u < 8) hv0[u] = h; else hv1[u - 8] = h;
  }
  size_t ro = ((size_t)(b * 4096 + i0 + il)) * 256 + c0 + ch * 16;
  *(s16x8*)(xt + ro) = hv0;
  *(s16x8*)(xt + ro + 8) = hv1;
}

// ----------------------- Q/K projection (3-term split) ---------------------
// out[i][c] = scale * (sum_c' hn[c'][i] W[c][c'] + bias[c]); q gets SCALE_Q.
__global__ __launch_bounds__(256) void proj_qk_k(
    const short* __restrict__ hn_hi, const short* __restrict__ hn_lo,
    const short* __restrict__ whi, const short* __restrict__ wlo,
    const float* __restrict__ bq, const float* __restrict__ bk,
    short* __restrict__ q_hi, short* __restrict__ q_lo,
    short* __restrict__ k_hi, short* __restrict__ k_lo) {
  int tid = threadIdx.x, w = tid >> 6, lane = tid & 63, l4 = lane & 15, g = lane >> 4;
  int iblk = blockIdx.x, y = blockIdx.y, b = blockIdx.z;
  const short* wh = whi + y * 65536;
  const short* wl = wlo + y * 65536;
  const float* bias = y ? bk : bq;
  short* ohi = (y ? k_hi : q_hi) + (size_t)b * 1048576;
  short* olo = (y ? k_lo : q_lo) + (size_t)b * 1048576;
  float scale = y ? 1.0f : SCALE_Q;
  int arow = iblk * 64 + w * 16 + l4;
  const short* ha = hn_hi + ((size_t)(b * 4096 + arow)) * 256 + g * 8;
  const short* la = hn_lo + ((size_t)(b * 4096 + arow)) * 256 + g * 8;
  f32x4 acc[16];
#pragma unroll
  for (int i = 0; i < 16; ++i) acc[i] = (f32x4){0.f, 0.f, 0.f, 0.f};
  for (int ks = 0; ks < 8; ++ks) {
    bf16x8 ah = *(const bf16x8*)(ha + ks * 32);
    bf16x8 al = *(const bf16x8*)(la + ks * 32);
#pragma unroll
    for (int ct = 0; ct < 16; ++ct) {
      bf16x8 bh = *(const bf16x8*)(wh + (ct * 16 + l4) * 256 + ks * 32 + g * 8);
      bf16x8 bl = *(const bf16x8*)(wl + (ct * 16 + l4) * 256 + ks * 32 + g * 8);
      acc[ct] = MFMA16(ah, bh, acc[ct]);
      acc[ct] = MFMA16(al, bh, acc[ct]);
      acc[ct] = MFMA16(ah, bl, acc[ct]);
    }
  }
  int orow = iblk * 64 + w * 16 + g * 4;
#pragma unroll
  for (int ct = 0; ct < 16; ++ct) {
    int c = ct * 16 + l4;
    float bsv = bias[c];
#pragma unroll
    for (int r = 0; r < 4; ++r) {
      float val = (acc[ct][r] + bsv) * scale;
      short h = f2bf(val);
      short lo = f2bf(val - bf2f(h));
      size_t off = ((size_t)(orow + r)) * 256 + c;
      ohi[off] = h;
      olo[off] = lo;
    }
  }
}

// ----------------------------- V projection --------------------------------
// v[c][j] = sum_c' Wv[c][c'] hn[c'][j] + bv[c]   (plain bf16)
__global__ __launch_bounds__(256) void proj_v_k(
    const short* __restrict__ hn_hi, const short* __restrict__ wv_hi,
    const float* __restrict__ bv, short* __restrict__ vout) {
  int tid = threadIdx.x, w = tid >> 6, lane = tid & 63, l4 = lane & 15, g = lane >> 4;
  int jblk = blockIdx.x, cblk = blockIdx.y, b = blockIdx.z;
  int crow = cblk * 64 + w * 16 + l4;
  const short* ap = wv_hi + (size_t)crow * 256 + g * 8;
  f32x4 acc[4];
#pragma unroll
  for (int i = 0; i < 4; ++i) acc[i] = (f32x4){0.f, 0.f, 0.f, 0.f};
  for (int ks = 0; ks < 8; ++ks) {
    bf16x8 a = *(const bf16x8*)(ap + ks * 32);
#pragma unroll
    for (int jt = 0; jt < 4; ++jt) {
      bf16x8 bb = *(const bf16x8*)(hn_hi +
          ((size_t)(b * 4096 + jblk * 64 + jt * 16 + l4)) * 256 + ks * 32 + g * 8);
      acc[jt] = MFMA16(a, bb, acc[jt]);
    }
  }
#pragma unroll
  for (int jt = 0; jt < 4; ++jt) {
#pragma unroll
    for (int r = 0; r < 4; ++r) {
      int c = cblk * 64 + w * 16 + g * 4 + r;
      int j = jblk * 64 + jt * 16 + l4;
      float val = acc[jt][r] + bv[c];
      vout[((size_t)(b * 256 + c)) * 4096 + j] = f2bf(val);
    }
  }
}

// ------------------------- out-projection (Wo . x) -------------------------
__global__ __launch_bounds__(256) void outproj_k(
    const short* __restrict__ xt, const short* __restrict__ wo_hi,
    const float* __restrict__ bo, float* __restrict__ out) {
  int tid = threadIdx.x, w = tid >> 6, lane = tid & 63, l4 = lane & 15, g = lane >> 4;
  int jblk = blockIdx.x, cblk = blockIdx.y, b = blockIdx.z;
  int crow = cblk * 64 + w * 16 + l4;
  const short* ap = wo_hi + (size_t)crow * 256 + g * 8;
  f32x4 acc[4];
#pragma unroll
  for (int i = 0; i < 4; ++i) acc[i] = (f32x4){0.f, 0.f, 0.f, 0.f};
  for (int ks = 0; ks < 8; ++ks) {
    bf16x8 a = *(const bf16x8*)(ap + ks * 32);
#pragma unroll
    for (int jt = 0; jt < 4; ++jt) {
      bf16x8 bb = *(const bf16x8*)(xt +
          ((size_t)(b * 4096 + jblk * 64 + jt * 16 + l4)) * 256 + ks * 32 + g * 8);
      acc[jt] = MFMA16(a, bb, acc[jt]);
    }
  }
#pragma unroll
  for (int jt = 0; jt < 4; ++jt) {
#pragma unroll
    for (int r = 0; r < 4; ++r) {
      int c = cblk * 64 + w * 16 + g * 4 + r;
      int j = jblk * 64 + jt * 16 + l4;
      out[((size_t)(b * 256 + c)) * 4096 + j] = acc[jt][r] + bo[c];
    }
  }
}

// ------------------------------ flash attention ----------------------------
// Per block: 64 q-rows (4 waves x 16), loop 128 j-steps of 32 keys.
// S^T = mfma(K_frag, Q_frag) so each lane holds one q-row's scores.
// q pre-scaled by -128*log2e -> softmax via exp2. Deferred-max online softmax.
__global__ __launch_bounds__(256, 2) void flash_k(
    const short* __restrict__ qhi, const short* __restrict__ qlo,
    const short* __restrict__ khi, const short* __restrict__ klo,
    const short* __restrict__ vv, float* __restrict__ out) {
  __shared__ short k_hi_s[8192];   // [32 j][256 c], row-XOR-swizzled, 16KB
  __shared__ short k_lo_s[8192];
  __shared__ short v_s[8192];      // [256 c][32 j], chunk-XOR-swizzled, 16KB
  __shared__ short p_s[2560];      // per-wave [16 i][40 j] bf16

  int tid = threadIdx.x, w = tid >> 6, lane = tid & 63, l4 = lane & 15, g = lane >> 4;
  int b = blockIdx.y, i0 = blockIdx.x * 64;
  size_t boff = (size_t)b * 1048576;
  const short* qh_p = qhi + boff;
  const short* ql_p = qlo + boff;
  const char* kh_g = (const char*)(khi + boff);
  const char* kl_g = (const char*)(klo + boff);
  const char* v_g = (const char*)(vv + boff);

  // hoist Q fragments (B-operand: lane holds col i = l4, k contiguous)
  int qrow = i0 + w * 16 + l4;
  bf16x8 qh[8], ql[8];
#pragma unroll
  for (int ks = 0; ks < 8; ++ks) {
    qh[ks] = *(const bf16x8*)(qh_p + (size_t)qrow * 256 + ks * 32 + g * 8);
    ql[ks] = *(const bf16x8*)(ql_p + (size_t)qrow * 256 + ks * 32 + g * 8);
  }

  f32x4 oac[16];
#pragma unroll
  for (int i = 0; i < 16; ++i) oac[i] = (f32x4){0.f, 0.f, 0.f, 0.f};
  float m_cur = -1e30f, lsum = 0.f;

  // precomputed LDS byte offsets
  int sx = (l4 & 7) << 4;
  int colx[8];
#pragma unroll
  for (int ks = 0; ks < 8; ++ks) colx[ks] = (ks * 64 + g * 16) ^ sx;
  int krow_b = l4 * 512;
  int vx = l4 * 64 + ((g ^ (l4 & 3)) << 4);
  int pwb = w * 1280 + l4 * 80 + g * 8;
  int prb = w * 1280 + l4 * 80 + g * 16;

  // staging: pre-swizzled per-thread global source offsets (LDS dest linear)
  int ksrc[4], vsrc[4];
#pragma unroll
  for (int it = 0; it < 4; ++it) {
    int d = tid * 16 + it * 4096;
    int krow = d >> 9, kcol = d & 511;
    ksrc[it] = krow * 512 + (kcol ^ ((krow & 7) << 4));
    int vrow = d >> 6, vch = (d >> 4) & 3;
    vsrc[it] = vrow * 8192 + ((vch ^ (vrow & 3)) << 4);
  }

  char* khs = (char*)k_hi_s;
  char* kls = (char*)k_lo_s;
  char* vs = (char*)v_s;
  char* ps = (char*)p_s;

  for (int js = 0; js < 128; ++js) {
    int kgo = js * 16384;  // j0*512 bytes
    int vgo = js * 64;     // j0*2 bytes
    __syncthreads();
#pragma unroll
    for (int it = 0; it < 4; ++it) {
      int ldst = w * 1024 + it * 4096;  // wave-uniform base; HW adds lane*16
      async16(khs + ldst, kh_g + kgo + ksrc[it]);
      async16(kls + ldst, kl_g + kgo + ksrc[it]);
      async16(vs + ldst, v_g + vgo + vsrc[it]);
    }
    __syncthreads();

    // S^T tiles: rows j (2 tiles of 16), cols i (wave's 16 rows)
    f32x4 st0 = (f32x4){0.f, 0.f, 0.f, 0.f};
    f32x4 st1 = (f32x4){0.f, 0.f, 0.f, 0.f};
#pragma unroll
    for (int ks = 0; ks < 8; ++ks) {
      bf16x8 kh0 = *(const bf16x8*)(khs + krow_b + colx[ks]);
      bf16x8 kh1 = *(const bf16x8*)(khs + krow_b + colx[ks] + 8192);
      bf16x8 kl0 = *(const bf16x8*)(kls + krow_b + colx[ks]);
      bf16x8 kl1 = *(const bf16x8*)(kls + krow_b + colx[ks] + 8192);
      st0 = MFMA16(kh0, qh[ks], st0);
      st1 = MFMA16(kh1, qh[ks], st1);
      st0 = MFMA16(kl0, qh[ks], st0);
      st1 = MFMA16(kl1, qh[ks], st1);
      st0 = MFMA16(kh0, ql[ks], st0);
      st1 = MFMA16(kh1, ql[ks], st1);
    }

    // online softmax (lane owns row i = l4, 8 keys; reduce over 4 lane-groups)
    float pmax = fmaxf(fmaxf(fmaxf(st0[0], st0[1]), fmaxf(st0[2], st0[3])),
                       fmaxf(fmaxf(st1[0], st1[1]), fmaxf(st1[2], st1[3])));
    pmax = fmaxf(pmax, __shfl_xor(pmax, 16));
    pmax = fmaxf(pmax, __shfl_xor(pmax, 32));
    if (!__all(pmax <= m_cur + 11.0f)) {
      float m_new = fmaxf(m_cur, pmax);
      float al = exp2f(m_cur - m_new);
      lsum *= al;
      int rb = g * 4;
      f32x4 av;
      av[0] = __shfl(al, rb);
      av[1] = __shfl(al, rb + 1);
      av[2] = __shfl(al, rb + 2);
      av[3] = __shfl(al, rb + 3);
#pragma unroll
      for (int ct = 0; ct < 16; ++ct) oac[ct] *= av;
      m_cur = m_new;
    }
    f32x4 e0, e1;
#pragma unroll
    for (int r = 0; r < 4; ++r) {
      e0[r] = exp2f(st0[r] - m_cur);
      e1[r] = exp2f(st1[r] - m_cur);
    }
    float lps = e0[0] + e0[1] + e0[2] + e0[3] + e1[0] + e1[1] + e1[2] + e1[3];
    lps += __shfl_xor(lps, 16);
    lps += __shfl_xor(lps, 32);
    lsum += lps;

    // P -> bf16 -> wave-private LDS, re-read as PV A-fragment
    s16x4 pw0 = {f2bf(e0[0]), f2bf(e0[1]), f2bf(e0[2]), f2bf(e0[3])};
    s16x4 pw1 = {f2bf(e1[0]), f2bf(e1[1]), f2bf(e1[2]), f2bf(e1[3])};
    *(s16x4*)(ps + pwb) = pw0;
    *(s16x4*)(ps + pwb + 32) = pw1;
    bf16x8 pa = *(const bf16x8*)(ps + prb);
#pragma unroll
    for (int ct = 0; ct < 16; ++ct) {
      bf16x8 vb = *(const bf16x8*)(vs + vx + ct * 1024);
      oac[ct] = MFMA16(pa, vb, oac[ct]);
    }
  }

  // epilogue: divide by row-sum, add out-projection already in d_out
  f32x4 inv;
  {
    int rb = g * 4;
    inv[0] = 1.f / __shfl(lsum, rb);
    inv[1] = 1.f / __shfl(lsum, rb + 1);
    inv[2] = 1.f / __shfl(lsum, rb + 2);
    inv[3] = 1.f / __shfl(lsum, rb + 3);
  }
  float* ob = out + (size_t)b * 1048576;
  int irow = i0 + w * 16 + g * 4;
#pragma unroll
  for (int ct = 0; ct < 16; ++ct) {
    float* ad = ob + (size_t)(ct * 16 + l4) * 4096 + irow;
    f32x4 prev = *(const f32x4*)ad;
    f32x4 res;
#pragma unroll
    for (int r = 0; r < 4; ++r) res[r] = prev[r] + oac[ct][r] * inv[r];
    *(f32x4*)ad = res;
  }
}

// ---------------------------------------------------------------------------
extern "C" void kernel_launch(void* const* d_in, const int* in_sizes, int n_in,
                              void* d_out, int out_size, void* d_ws, size_t ws_size,
                              hipStream_t stream) {
  (void)in_sizes; (void)n_in; (void)out_size; (void)ws_size;
  const float* x = (const float*)d_in[0];
  const float* gamma = (const float*)d_in[1];
  const float* beta = (const float*)d_in[2];
  const float* Wq = (const float*)d_in[3];
  const float* bq = (const float*)d_in[4];
  const float* Wk = (const float*)d_in[5];
  const float* bk = (const float*)d_in[6];
  const float* Wv = (const float*)d_in[7];
  const float* bv = (const float*)d_in[8];
  const float* Wo = (const float*)d_in[9];
  const float* bo = (const float*)d_in[10];
  float* out = (float*)d_out;
  char* ws = (char*)d_ws;

  const size_t MB16 = 16777216;  // 8*4096*256 bf16
  float* stats = (float*)(ws);                      // 2KB
  short* whi = (short*)(ws + 4096);                 // 4 * 64K shorts
  short* wlo = (short*)(ws + 4096 + 524288);
  char* base = ws + 4096 + 2 * 524288;
  short* hnhi = (short*)(base);
  short* hnlo = (short*)(base + MB16);
  short* qhi = (short*)(base + 2 * MB16);
  short* qlo = (short*)(base + 3 * MB16);
  short* khi = (short*)(base + 4 * MB16);
  short* klo = (short*)(base + 5 * MB16);
  short* vvp = (short*)(base + 6 * MB16);
  short* xt = hnhi;  // alias: hnT dead after projections (stream-ordered)

  wsplit_k<<<dim3(1024), dim3(256), 0, stream>>>(Wq, Wk, Wv, Wo, whi, wlo);
  gn_stats_k<<<dim3(256), dim3(256), 0, stream>>>(x, stats);
  gn_apply_k<<<dim3(64, 4, 8), dim3(256), 0, stream>>>(x, gamma, beta, stats, hnhi, hnlo);
  proj_qk_k<<<dim3(64, 2, 8), dim3(256), 0, stream>>>(hnhi, hnlo, whi, wlo, bq, bk,
                                                      qhi, qlo, khi, klo);
  proj_v_k<<<dim3(64, 4, 8), dim3(256), 0, stream>>>(hnhi, whi + 2 * 65536, bv, vvp);
  xt_k<<<dim3(64, 4, 8), dim3(256), 0, stream>>>(x, xt);
  outproj_k<<<dim3(64, 4, 8), dim3(256), 0, stream>>>(xt, whi + 3 * 65536, bo, out);
  flash_k<<<dim3(64, 8), dim3(256), 0, stream>>>(qhi, qlo, khi, klo, vvp, out);
}

// Round 3
// 537.299 us; speedup vs baseline: 1.0447x; 1.0447x over previous
//
#include <hip/hip_runtime.h>
#include <hip/hip_bf16.h>

// ---------------------------------------------------------------------------
// AttentionBlock: GroupNorm -> q,k,v 1x1 conv -> softmax(-128 * q^T k) -> PV
//                 + conv1x1(x, Wo)
// B=8, C=256, HW=4096, 32 groups. fp32 in/out.
// Scores need bf16x2 split (3-MFMA) path; V/PV/out-proj plain bf16.
// flash3: K double-buffered async staging; same-iteration c-split PV
//         (P through a single un-pipelined LDS buffer); V prefetched from
//         global into registers; fused Wo*x epilogue. No LDS state crosses
//         an iteration boundary.
// ---------------------------------------------------------------------------

typedef __attribute__((ext_vector_type(8))) short bf16x8;
typedef __attribute__((ext_vector_type(4))) short s16x4;
typedef __attribute__((ext_vector_type(8))) short s16x8;
typedef __attribute__((ext_vector_type(4))) float f32x4;

#define MFMA16(a, b, c) __builtin_amdgcn_mfma_f32_16x16x32_bf16((a), (b), (c), 0, 0, 0)

// -0.5 * C * log2(e): fold attention scale (and exp->exp2) into q.
#define SCALE_Q (-184.66496523378734f)

__device__ __forceinline__ short f2bf(float f) {
  unsigned int u = __builtin_bit_cast(unsigned int, f);
  u = (u + 0x7FFFu + ((u >> 16) & 1u)) >> 16;
  return (short)(unsigned short)u;
}
__device__ __forceinline__ float bf2f(short h) {
  unsigned int u = ((unsigned int)(unsigned short)h) << 16;
  return __builtin_bit_cast(float, u);
}
__device__ __forceinline__ void async16(void* lds, const void* g) {
  __builtin_amdgcn_global_load_lds(
      (const __attribute__((address_space(1))) unsigned int*)g,
      (__attribute__((address_space(3))) unsigned int*)lds, 16, 0, 0);
}

// --------------------------- W -> hi/lo bf16 split -------------------------
__global__ void wsplit_k(const float* __restrict__ Wq, const float* __restrict__ Wk,
                         const float* __restrict__ Wv, const float* __restrict__ Wo,
                         short* __restrict__ whi, short* __restrict__ wlo) {
  int idx = blockIdx.x * 256 + threadIdx.x;   // 0 .. 4*65536-1
  int m = idx >> 16;
  int e = idx & 65535;
  const float* W = (m == 0) ? Wq : (m == 1) ? Wk : (m == 2) ? Wv : Wo;
  float v = W[e];
  short h = f2bf(v);
  whi[idx] = h;
  wlo[idx] = f2bf(v - bf2f(h));
}

// --------------------------- GroupNorm stats -------------------------------
__global__ void gn_stats_k(const float* __restrict__ x, float* __restrict__ stats) {
  int bg = blockIdx.x;          // b*32 + g, contiguous 32768 floats
  int tid = threadIdx.x;
  const float* p = x + (size_t)bg * 32768;
  float s = 0.f, sq = 0.f;
  for (int it = 0; it < 32; ++it) {
    f32x4 v = *(const f32x4*)(p + (size_t)(it * 256 + tid) * 4);
    s += v[0] + v[1] + v[2] + v[3];
    sq += v[0] * v[0] + v[1] * v[1] + v[2] * v[2] + v[3] * v[3];
  }
#pragma unroll
  for (int off = 1; off < 64; off <<= 1) {
    s += __shfl_xor(s, off);
    sq += __shfl_xor(sq, off);
  }
  __shared__ float ls[4], lq[4];
  int w = tid >> 6;
  if ((tid & 63) == 0) { ls[w] = s; lq[w] = sq; }
  __syncthreads();
  if (tid == 0) {
    float S = ls[0] + ls[1] + ls[2] + ls[3];
    float Q = lq[0] + lq[1] + lq[2] + lq[3];
    float mean = S * (1.f / 32768.f);
    float var = Q * (1.f / 32768.f) - mean * mean;
    stats[bg * 2] = mean;
    stats[bg * 2 + 1] = rsqrtf(var + 1e-5f);
  }
}

// ------------------- GroupNorm apply + transpose + split -------------------
// x[b][c][i] fp32 -> hnT[b][i][c] bf16 hi/lo  (c contiguous)
__global__ void gn_apply_k(const float* __restrict__ x, const float* __restrict__ gamma,
                           const float* __restrict__ beta, const float* __restrict__ stats,
                           short* __restrict__ hn_hi, short* __restrict__ hn_lo) {
  __shared__ float tile[64 * 68];
  int tid = threadIdx.x;
  int b = blockIdx.z, c0 = blockIdx.y * 64, i0 = blockIdx.x * 64;
  int cc = tid >> 4, ich = tid & 15;
#pragma unroll
  for (int it = 0; it < 4; ++it) {
    int c = c0 + cc + it * 16;
    f32x4 vx = *(const f32x4*)(x + ((size_t)(b * 256 + c)) * 4096 + i0 + ich * 4);
    float mean = stats[(b * 32 + (c >> 3)) * 2];
    float rstd = stats[(b * 32 + (c >> 3)) * 2 + 1];
    float ga = gamma[c] * rstd;
    float be = beta[c] - mean * ga;
    f32x4 h = {vx[0] * ga + be, vx[1] * ga + be, vx[2] * ga + be, vx[3] * ga + be};
    *(f32x4*)(&tile[(cc + it * 16) * 68 + ich * 4]) = h;
  }
  __syncthreads();
  int il = tid >> 2, ch = tid & 3;
  s16x8 hv0, hv1, lv0, lv1;
#pragma unroll
  for (int u = 0; u < 16; ++u) {
    float vv = tile[(ch * 16 + u) * 68 + il];
    short h = f2bf(vv);
    short lo = f2bf(vv - bf2f(h));
    if (u < 8) { hv0[u] = h; lv0[u] = lo; } else { hv1[u - 8] = h; lv1[u - 8] = lo; }
  }
  size_t ro = ((size_t)(b * 4096 + i0 + il)) * 256 + c0 + ch * 16;
  *(s16x8*)(hn_hi + ro) = hv0;
  *(s16x8*)(hn_hi + ro + 8) = hv1;
  *(s16x8*)(hn_lo + ro) = lv0;
  *(s16x8*)(hn_lo + ro + 8) = lv1;
}

// ----------------------- Q/K projection (3-term split) ---------------------
__global__ __launch_bounds__(256) void proj_qk_k(
    const short* __restrict__ hn_hi, const short* __restrict__ hn_lo,
    const short* __restrict__ whi, const short* __restrict__ wlo,
    const float* __restrict__ bq, const float* __restrict__ bk,
    short* __restrict__ q_hi, short* __restrict__ q_lo,
    short* __restrict__ k_hi, short* __restrict__ k_lo) {
  int tid = threadIdx.x, w = tid >> 6, lane = tid & 63, l4 = lane & 15, g = lane >> 4;
  int iblk = blockIdx.x, y = blockIdx.y, b = blockIdx.z;
  const short* wh = whi + y * 65536;
  const short* wl = wlo + y * 65536;
  const float* bias = y ? bk : bq;
  short* ohi = (y ? k_hi : q_hi) + (size_t)b * 1048576;
  short* olo = (y ? k_lo : q_lo) + (size_t)b * 1048576;
  float scale = y ? 1.0f : SCALE_Q;
  int arow = iblk * 64 + w * 16 + l4;
  const short* ha = hn_hi + ((size_t)(b * 4096 + arow)) * 256 + g * 8;
  const short* la = hn_lo + ((size_t)(b * 4096 + arow)) * 256 + g * 8;
  f32x4 acc[16];
#pragma unroll
  for (int i = 0; i < 16; ++i) acc[i] = (f32x4){0.f, 0.f, 0.f, 0.f};
  for (int ks = 0; ks < 8; ++ks) {
    bf16x8 ah = *(const bf16x8*)(ha + ks * 32);
    bf16x8 al = *(const bf16x8*)(la + ks * 32);
#pragma unroll
    for (int ct = 0; ct < 16; ++ct) {
      bf16x8 bh = *(const bf16x8*)(wh + (ct * 16 + l4) * 256 + ks * 32 + g * 8);
      bf16x8 bl = *(const bf16x8*)(wl + (ct * 16 + l4) * 256 + ks * 32 + g * 8);
      acc[ct] = MFMA16(ah, bh, acc[ct]);
      acc[ct] = MFMA16(al, bh, acc[ct]);
      acc[ct] = MFMA16(ah, bl, acc[ct]);
    }
  }
  int orow = iblk * 64 + w * 16 + g * 4;
#pragma unroll
  for (int ct = 0; ct < 16; ++ct) {
    int c = ct * 16 + l4;
    float bsv = bias[c];
#pragma unroll
    for (int r = 0; r < 4; ++r) {
      float val = (acc[ct][r] + bsv) * scale;
      short h = f2bf(val);
      short lo = f2bf(val - bf2f(h));
      size_t off = ((size_t)(orow + r)) * 256 + c;
      ohi[off] = h;
      olo[off] = lo;
    }
  }
}

// ----------------------------- V projection --------------------------------
__global__ __launch_bounds__(256) void proj_v_k(
    const short* __restrict__ hn_hi, const short* __restrict__ wv_hi,
    const float* __restrict__ bv, short* __restrict__ vout) {
  int tid = threadIdx.x, w = tid >> 6, lane = tid & 63, l4 = lane & 15, g = lane >> 4;
  int jblk = blockIdx.x, cblk = blockIdx.y, b = blockIdx.z;
  int crow = cblk * 64 + w * 16 + l4;
  const short* ap = wv_hi + (size_t)crow * 256 + g * 8;
  f32x4 acc[4];
#pragma unroll
  for (int i = 0; i < 4; ++i) acc[i] = (f32x4){0.f, 0.f, 0.f, 0.f};
  for (int ks = 0; ks < 8; ++ks) {
    bf16x8 a = *(const bf16x8*)(ap + ks * 32);
#pragma unroll
    for (int jt = 0; jt < 4; ++jt) {
      bf16x8 bb = *(const bf16x8*)(hn_hi +
          ((size_t)(b * 4096 + jblk * 64 + jt * 16 + l4)) * 256 + ks * 32 + g * 8);
      acc[jt] = MFMA16(a, bb, acc[jt]);
    }
  }
#pragma unroll
  for (int jt = 0; jt < 4; ++jt) {
#pragma unroll
    for (int r = 0; r < 4; ++r) {
      int c = cblk * 64 + w * 16 + g * 4 + r;
      int j = jblk * 64 + jt * 16 + l4;
      float val = acc[jt][r] + bv[c];
      vout[((size_t)(b * 256 + c)) * 4096 + j] = f2bf(val);
    }
  }
}

// ------------------------------ flash attention v3 -------------------------
// Per block: 64 q-rows. S: 4 waves x 16 rows each. PV: c-split, wave owns
// 64 c x 64 i. All softmax state consumed in the same iteration (no LDS
// state crosses iterations). K hi/lo double-buffered via global_load_lds.
__global__ __launch_bounds__(256, 2) void flash3_k(
    const short* __restrict__ qhi, const short* __restrict__ qlo,
    const short* __restrict__ khi, const short* __restrict__ klo,
    const short* __restrict__ vv, const float* __restrict__ x,
    const short* __restrict__ wo_hi, const float* __restrict__ bo,
    float* __restrict__ out) {
  __shared__ short k_hi_s[2][8192];  // [dbuf][32 j][256 c], row-XOR-swizzled
  __shared__ short k_lo_s[2][8192];
  __shared__ short p_s[2048];        // [64 i][32 j] bf16, linear
  __shared__ __attribute__((aligned(16))) float albuf[64];
  __shared__ __attribute__((aligned(16))) float flagbuf[4];
  __shared__ __attribute__((aligned(16))) float lsmbuf[64];

  int tid = threadIdx.x, w = tid >> 6, lane = tid & 63, l4 = lane & 15, g = lane >> 4;
  int b = blockIdx.y, i0 = blockIdx.x * 64;
  size_t boff = (size_t)b * 1048576;
  const short* qh_p = qhi + boff;
  const short* ql_p = qlo + boff;
  const char* kh_g = (const char*)(khi + boff);
  const char* kl_g = (const char*)(klo + boff);
  const short* v_p = vv + boff;

  // hoist Q fragments (B-operand: lane holds col i = l4, k contiguous)
  int qrow = i0 + w * 16 + l4;
  bf16x8 qh[8], ql[8];
#pragma unroll
  for (int ks = 0; ks < 8; ++ks) {
    qh[ks] = *(const bf16x8*)(qh_p + (size_t)qrow * 256 + ks * 32 + g * 8);
    ql[ks] = *(const bf16x8*)(ql_p + (size_t)qrow * 256 + ks * 32 + g * 8);
  }

  f32x4 oac[4][4];   // [i-tile][c-tile]; i = it*16+g*4+r, c = w*64+ct*16+l4
#pragma unroll
  for (int it = 0; it < 4; ++it)
#pragma unroll
    for (int ct = 0; ct < 4; ++ct) oac[it][ct] = (f32x4){0.f, 0.f, 0.f, 0.f};
  float m_cur = -1e30f, lsum = 0.f;

  int sx = (l4 & 7) << 4;
  int colx[8];
#pragma unroll
  for (int ks = 0; ks < 8; ++ks) colx[ks] = (ks * 64 + g * 16) ^ sx;
  int krow_b = l4 * 512;

  // staging: pre-swizzled per-thread global source offsets (LDS dest linear)
  int ksrc[4];
#pragma unroll
  for (int it = 0; it < 4; ++it) {
    int d = tid * 16 + it * 4096;
    int krow = d >> 9, kcol = d & 511;
    ksrc[it] = krow * 512 + (kcol ^ ((krow & 7) << 4));
  }

  char* khs = (char*)k_hi_s;
  char* kls = (char*)k_lo_s;
  char* ps = (char*)p_s;
  int cbase = w * 64;
  bf16x8 vreg[4];

  // prologue: stage K(0) into buffer 0
#pragma unroll
  for (int it = 0; it < 4; ++it) {
    int ldst = w * 1024 + it * 4096;
    async16(khs + ldst, kh_g + ksrc[it]);
    async16(kls + ldst, kl_g + ksrc[it]);
  }

  for (int js = 0; js < 128; ++js) {
    int cur = (js & 1) * 16384;
    __syncthreads();   // B1: K(js) staged (vmcnt drained); p_s free for reuse
    if (js < 127) {
      int kgo = (js + 1) * 16384;
      int nxt = ((js + 1) & 1) * 16384;
#pragma unroll
      for (int it = 0; it < 4; ++it) {
        int ldst = nxt + w * 1024 + it * 4096;  // wave-uniform base + lane*16
        async16(khs + ldst, kh_g + kgo + ksrc[it]);
        async16(kls + ldst, kl_g + kgo + ksrc[it]);
      }
    }
    // prefetch V(js) B-fragments from global (consumed after B2)
#pragma unroll
    for (int ct = 0; ct < 4; ++ct)
      vreg[ct] = *(const bf16x8*)(v_p + (size_t)(cbase + ct * 16 + l4) * 4096 +
                                  js * 32 + g * 8);

    // S^T tiles: rows j (2 tiles of 16), cols i (wave's 16 rows)
    f32x4 st0 = (f32x4){0.f, 0.f, 0.f, 0.f};
    f32x4 st1 = (f32x4){0.f, 0.f, 0.f, 0.f};
    __builtin_amdgcn_s_setprio(1);
#pragma unroll
    for (int ks = 0; ks < 8; ++ks) {
      bf16x8 kh0 = *(const bf16x8*)(khs + cur + krow_b + colx[ks]);
      bf16x8 kh1 = *(const bf16x8*)(khs + cur + krow_b + colx[ks] + 8192);
      bf16x8 kl0 = *(const bf16x8*)(kls + cur + krow_b + colx[ks]);
      bf16x8 kl1 = *(const bf16x8*)(kls + cur + krow_b + colx[ks] + 8192);
      st0 = MFMA16(kh0, qh[ks], st0);
      st1 = MFMA16(kh1, qh[ks], st1);
      st0 = MFMA16(kl0, qh[ks], st0);
      st1 = MFMA16(kl1, qh[ks], st1);
      st0 = MFMA16(kh0, ql[ks], st0);
      st1 = MFMA16(kh1, ql[ks], st1);
    }
    __builtin_amdgcn_s_setprio(0);

    // online softmax (lane owns row i = l4; reduce over 4 lane-groups g)
    float pmax = fmaxf(fmaxf(fmaxf(st0[0], st0[1]), fmaxf(st0[2], st0[3])),
                       fmaxf(fmaxf(st1[0], st1[1]), fmaxf(st1[2], st1[3])));
    pmax = fmaxf(pmax, __shfl_xor(pmax, 16));
    pmax = fmaxf(pmax, __shfl_xor(pmax, 32));
    float alpha = 1.0f;
    bool upd = !__all(pmax <= m_cur + 11.0f);
    if (upd) {
      float m_new = fmaxf(m_cur, pmax);
      alpha = exp2f(m_cur - m_new);
      lsum *= alpha;
      m_cur = m_new;
    }
    f32x4 e0, e1;
#pragma unroll
    for (int r = 0; r < 4; ++r) {
      e0[r] = exp2f(st0[r] - m_cur);
      e1[r] = exp2f(st1[r] - m_cur);
    }
    float lps = e0[0] + e0[1] + e0[2] + e0[3] + e1[0] + e1[1] + e1[2] + e1[3];
    lps += __shfl_xor(lps, 16);
    lps += __shfl_xor(lps, 32);
    lsum += lps;

    // write P(js) linear: row i = w*16+l4; pw0 -> j g*4.., pw1 -> j 16+g*4..
    s16x4 pw0 = {f2bf(e0[0]), f2bf(e0[1]), f2bf(e0[2]), f2bf(e0[3])};
    s16x4 pw1 = {f2bf(e1[0]), f2bf(e1[1]), f2bf(e1[2]), f2bf(e1[3])};
    int wb = (w * 16 + l4) * 64 + g * 8;
    *(s16x4*)(ps + wb) = pw0;
    *(s16x4*)(ps + wb + 32) = pw1;
    if (lane < 16) albuf[w * 16 + lane] = alpha;
    if (lane == 0) flagbuf[w] = upd ? 1.f : 0.f;

    __syncthreads();   // B2: P/alpha/flag of js visible to all waves

    // PV(js): rescale by alpha(js), then accumulate P(js) * V(js)
    f32x4 fl = *(const f32x4*)(&flagbuf[0]);
    if (fl[0] + fl[1] + fl[2] + fl[3] > 0.f) {
#pragma unroll
      for (int it = 0; it < 4; ++it) {
        f32x4 av = *(const f32x4*)(&albuf[it * 16 + g * 4]);
#pragma unroll
        for (int ct = 0; ct < 4; ++ct)
#pragma unroll
          for (int r = 0; r < 4; ++r) oac[it][ct][r] *= av[r];
      }
    }
#pragma unroll
    for (int it = 0; it < 4; ++it) {
      bf16x8 pf = *(const bf16x8*)(ps + (it * 16 + l4) * 64 + g * 16);
#pragma unroll
      for (int ct = 0; ct < 4; ++ct) oac[it][ct] = MFMA16(pf, vreg[ct], oac[it][ct]);
    }
  }

  // ---- epilogue: 1/lsum, fused Wo*x GEMM, write out ------------------------
  if (lane < 16) lsmbuf[w * 16 + lane] = lsum;
  __syncthreads();
#pragma unroll
  for (int it = 0; it < 4; ++it) {
    f32x4 lv = *(const f32x4*)(&lsmbuf[it * 16 + g * 4]);
    f32x4 iv = {1.f / lv[0], 1.f / lv[1], 1.f / lv[2], 1.f / lv[3]};
#pragma unroll
    for (int ct = 0; ct < 4; ++ct)
#pragma unroll
      for (int r = 0; r < 4; ++r) oac[it][ct][r] *= iv[r];
  }
  // Wo * x accumulated straight into oac (A = x^T fragments, B = Wo rows)
  const float* xb = x + (size_t)b * 1048576;
  for (int ks = 0; ks < 8; ++ks) {
    bf16x8 af[4], bfr[4];
#pragma unroll
    for (int it = 0; it < 4; ++it) {
#pragma unroll
      for (int e = 0; e < 8; ++e) {
        float xv = xb[(size_t)(ks * 32 + g * 8 + e) * 4096 + i0 + it * 16 + l4];
        af[it][e] = f2bf(xv);
      }
    }
#pragma unroll
    for (int ct = 0; ct < 4; ++ct)
      bfr[ct] = *(const bf16x8*)(wo_hi + (cbase + ct * 16 + l4) * 256 + ks * 32 + g * 8);
#pragma unroll
    for (int it = 0; it < 4; ++it)
#pragma unroll
      for (int ct = 0; ct < 4; ++ct) oac[it][ct] = MFMA16(af[it], bfr[ct], oac[it][ct]);
  }
  float* ob = out + (size_t)b * 1048576;
#pragma unroll
  for (int ct = 0; ct < 4; ++ct) {
    float bov = bo[cbase + ct * 16 + l4];
#pragma unroll
    for (int it = 0; it < 4; ++it) {
      float* ad = ob + (size_t)(cbase + ct * 16 + l4) * 4096 + i0 + it * 16 + g * 4;
      f32x4 res;
#pragma unroll
      for (int r = 0; r < 4; ++r) res[r] = oac[it][ct][r] + bov;
      *(f32x4*)ad = res;
    }
  }
}

// ---------------------------------------------------------------------------
extern "C" void kernel_launch(void* const* d_in, const int* in_sizes, int n_in,
                              void* d_out, int out_size, void* d_ws, size_t ws_size,
                              hipStream_t stream) {
  (void)in_sizes; (void)n_in; (void)out_size; (void)ws_size;
  const float* x = (const float*)d_in[0];
  const float* gamma = (const float*)d_in[1];
  const float* beta = (const float*)d_in[2];
  const float* Wq = (const float*)d_in[3];
  const float* bq = (const float*)d_in[4];
  const float* Wk = (const float*)d_in[5];
  const float* bk = (const float*)d_in[6];
  const float* Wv = (const float*)d_in[7];
  const float* bv = (const float*)d_in[8];
  const float* Wo = (const float*)d_in[9];
  const float* bo = (const float*)d_in[10];
  float* out = (float*)d_out;
  char* ws = (char*)d_ws;

  const size_t MB16 = 16777216;  // 8*4096*256 bf16
  float* stats = (float*)(ws);                      // 2KB
  short* whi = (short*)(ws + 4096);                 // 4 * 64K shorts
  short* wlo = (short*)(ws + 4096 + 524288);
  char* base = ws + 4096 + 2 * 524288;
  short* hnhi = (short*)(base);
  short* hnlo = (short*)(base + MB16);
  short* qhi = (short*)(base + 2 * MB16);
  short* qlo = (short*)(base + 3 * MB16);
  short* khi = (short*)(base + 4 * MB16);
  short* klo = (short*)(base + 5 * MB16);
  short* vvp = (short*)(base + 6 * MB16);

  wsplit_k<<<dim3(1024), dim3(256), 0, stream>>>(Wq, Wk, Wv, Wo, whi, wlo);
  gn_stats_k<<<dim3(256), dim3(256), 0, stream>>>(x, stats);
  gn_apply_k<<<dim3(64, 4, 8), dim3(256), 0, stream>>>(x, gamma, beta, stats, hnhi, hnlo);
  proj_qk_k<<<dim3(64, 2, 8), dim3(256), 0, stream>>>(hnhi, hnlo, whi, wlo, bq, bk,
                                                      qhi, qlo, khi, klo);
  proj_v_k<<<dim3(64, 4, 8), dim3(256), 0, stream>>>(hnhi, whi + 2 * 65536, bv, vvp);
  flash3_k<<<dim3(64, 8), dim3(256), 0, stream>>>(qhi, qlo, khi, klo, vvp, x,
                                                  whi + 3 * 65536, bo, out);
}